// Round 4
// baseline (469.946 us; speedup 1.0000x reference)
//
#include <hip/hip_runtime.h>
#include <hip/hip_bf16.h>
#include <math.h>
#include <stdint.h>

// ---------------------------------------------------------------------------
// MaskedContextSelector, round 4: uniform triangular score tiles.
//   K0a prep_hs  : hs_hi = bf16(hs); hsT_hi/lo = transposed bf16 hi/lo split
//   K0b cast_w   : Wq,Wk -> bf16
//   K1  proj_mfma: Q,K = bf16MFMA(hs_hi @ W^T) + bias -> bf16
//   K2a zpart    : z[b,h,t] partial sums via (16q x 128s) tiles + atomicAdd
//   K2b elgen    : same tiling; EL = exp((mean_h softmax_h + g)/TAU) hi/lo,
//                  L via atomicAdd. One barrier per block, no loops.
//   K3  out_mfma : out = (ELh@Hh + ELh@Hl + ELl@Hh)/L
// ---------------------------------------------------------------------------

#define B_   2
#define T_   2048
#define E_   1024
#define NH_  16
#define DH_  64
#define M_   (B_ * T_)
#define SCALE_ 0.125f

typedef __attribute__((ext_vector_type(8))) short bf16x8;
typedef __attribute__((ext_vector_type(4))) float f32x4;

__device__ __forceinline__ short f2bf(float x) {
  __hip_bfloat16 h = __float2bfloat16(x);
  return *reinterpret_cast<short*>(&h);
}
__device__ __forceinline__ float bf2f(short x) {
  __hip_bfloat16 h = *reinterpret_cast<__hip_bfloat16*>(&x);
  return __bfloat162float(h);
}

// ------------------- K0a: cast + transpose hidden states -------------------
__global__ __launch_bounds__(256) void prep_hs(
    const float* __restrict__ hs, short* __restrict__ hs_hi,
    short* __restrict__ hsT_hi, short* __restrict__ hsT_lo)
{
  const int b = blockIdx.z;
  const int s0 = blockIdx.x * 64, e0 = blockIdx.y * 64;
  __shared__ float tile[64][65];
  const int tid = threadIdx.x;
  const int r = tid >> 4, c4 = (tid & 15) * 4;

  #pragma unroll
  for (int rr = 0; rr < 64; rr += 16) {
    const float4 v = *(const float4*)(hs + (size_t)(b * T_ + s0 + r + rr) * E_ + e0 + c4);
    ushort4 o;
    o.x = (unsigned short)f2bf(v.x); o.y = (unsigned short)f2bf(v.y);
    o.z = (unsigned short)f2bf(v.z); o.w = (unsigned short)f2bf(v.w);
    *(ushort4*)(hs_hi + (size_t)(b * T_ + s0 + r + rr) * E_ + e0 + c4) = o;
    tile[r + rr][c4 + 0] = v.x; tile[r + rr][c4 + 1] = v.y;
    tile[r + rr][c4 + 2] = v.z; tile[r + rr][c4 + 3] = v.w;
  }
  __syncthreads();
  #pragma unroll
  for (int rr = 0; rr < 64; rr += 16) {
    ushort4 oh, ol;
    #pragma unroll
    for (int j = 0; j < 4; ++j) {
      const float v = tile[c4 + j][r + rr];
      const short hi = f2bf(v);
      const short lo = f2bf(v - bf2f(hi));
      ((unsigned short*)&oh)[j] = (unsigned short)hi;
      ((unsigned short*)&ol)[j] = (unsigned short)lo;
    }
    const size_t dst = (size_t)(b * E_ + e0 + r + rr) * T_ + s0 + c4;
    *(ushort4*)(hsT_hi + dst) = oh;
    *(ushort4*)(hsT_lo + dst) = ol;
  }
}

// ------------------------------ K0b: cast W --------------------------------
__global__ __launch_bounds__(256) void cast_w(
    const float* __restrict__ Wq, const float* __restrict__ Wk,
    short* __restrict__ Wqb, short* __restrict__ Wkb)
{
  const size_t i = ((size_t)blockIdx.x * 256 + threadIdx.x) * 4;
  const float4 q = *(const float4*)(Wq + i);
  const float4 k = *(const float4*)(Wk + i);
  ushort4 oq, ok;
  oq.x = (unsigned short)f2bf(q.x); oq.y = (unsigned short)f2bf(q.y);
  oq.z = (unsigned short)f2bf(q.z); oq.w = (unsigned short)f2bf(q.w);
  ok.x = (unsigned short)f2bf(k.x); ok.y = (unsigned short)f2bf(k.y);
  ok.z = (unsigned short)f2bf(k.z); ok.w = (unsigned short)f2bf(k.w);
  *(ushort4*)(Wqb + i) = oq;
  *(ushort4*)(Wkb + i) = ok;
}

// --------------------------- K1: projection MFMA ---------------------------
__global__ __launch_bounds__(256) void proj_mfma(
    const short* __restrict__ hsb,
    const short* __restrict__ Wqb, const short* __restrict__ Wkb,
    const float* __restrict__ bq, const float* __restrict__ bk,
    short* __restrict__ Qb, short* __restrict__ Kb)
{
  const int nt = blockIdx.x;
  const int m0 = blockIdx.y * 128;
  const bool isK = nt >= 8;
  const short* __restrict__ Wsel = isK ? Wkb : Wqb;
  const float* __restrict__ bsel = isK ? bk : bq;
  short* __restrict__ Csel = isK ? Kb : Qb;
  const int nb = (nt & 7) * 128;

  __shared__ __align__(16) unsigned short Asm[128][72];
  __shared__ __align__(16) unsigned short Bsm[128][72];

  const int tid = threadIdx.x;
  const int wid = tid >> 6, l = tid & 63;
  const int lg = l >> 4, li = l & 15;
  const int wm = (wid >> 1) * 64, wn = (wid & 1) * 64;
  const int srow = tid >> 1, shalf = (tid & 1) * 32;

  f32x4 acc[4][4];
  #pragma unroll
  for (int i = 0; i < 4; ++i)
    #pragma unroll
    for (int j = 0; j < 4; ++j) acc[i][j] = (f32x4){0.f, 0.f, 0.f, 0.f};

  for (int kt = 0; kt < E_; kt += 64) {
    const short* ga = hsb + (size_t)(m0 + srow) * E_ + kt + shalf;
    const short* gb = Wsel + (size_t)(nb + srow) * E_ + kt + shalf;
    bf16x8 a0 = *(const bf16x8*)(ga);      bf16x8 a1 = *(const bf16x8*)(ga + 8);
    bf16x8 a2 = *(const bf16x8*)(ga + 16); bf16x8 a3 = *(const bf16x8*)(ga + 24);
    bf16x8 b0 = *(const bf16x8*)(gb);      bf16x8 b1 = *(const bf16x8*)(gb + 8);
    bf16x8 b2 = *(const bf16x8*)(gb + 16); bf16x8 b3 = *(const bf16x8*)(gb + 24);
    __syncthreads();
    *(bf16x8*)&Asm[srow][shalf + 0]  = a0; *(bf16x8*)&Asm[srow][shalf + 8]  = a1;
    *(bf16x8*)&Asm[srow][shalf + 16] = a2; *(bf16x8*)&Asm[srow][shalf + 24] = a3;
    *(bf16x8*)&Bsm[srow][shalf + 0]  = b0; *(bf16x8*)&Bsm[srow][shalf + 8]  = b1;
    *(bf16x8*)&Bsm[srow][shalf + 16] = b2; *(bf16x8*)&Bsm[srow][shalf + 24] = b3;
    __syncthreads();
    #pragma unroll
    for (int kb = 0; kb < 2; ++kb) {
      bf16x8 af[4], bfv[4];
      #pragma unroll
      for (int i = 0; i < 4; ++i)
        af[i] = *(const bf16x8*)&Asm[wm + i * 16 + li][kb * 32 + lg * 8];
      #pragma unroll
      for (int j = 0; j < 4; ++j)
        bfv[j] = *(const bf16x8*)&Bsm[wn + j * 16 + li][kb * 32 + lg * 8];
      #pragma unroll
      for (int i = 0; i < 4; ++i)
        #pragma unroll
        for (int j = 0; j < 4; ++j)
          acc[i][j] = __builtin_amdgcn_mfma_f32_16x16x32_bf16(af[i], bfv[j], acc[i][j], 0, 0, 0);
    }
  }

  #pragma unroll
  for (int j = 0; j < 4; ++j) {
    const int n = nb + wn + j * 16 + li;
    const float bv = bsel[n];
    #pragma unroll
    for (int i = 0; i < 4; ++i) {
      #pragma unroll
      for (int r = 0; r < 4; ++r) {
        const int m = m0 + wm + i * 16 + lg * 4 + r;
        Csel[(size_t)m * E_ + n] = f2bf(acc[i][j][r] + bv);
      }
    }
  }
}

// ----------------- K2a: z partials, (16q x 128s) tiles ---------------------
// wave w: heads (w&1)*8..+8, cols s0+(w>>1)*64..+64. No loops, no LDS combine.
__global__ __launch_bounds__(256) void zpart_kernel(
    const short* __restrict__ Qb, const short* __restrict__ Kb,
    const int* __restrict__ clen, float* __restrict__ zs)
{
  const int b = blockIdx.z;
  const int t0 = blockIdx.x * 16;
  const int s0 = blockIdx.y * 128;
  const int tid = threadIdx.x;
  const int w = tid >> 6, l = tid & 63;
  const int lg = l >> 4, li = l & 15;
  const int hbase = (w & 1) * 8;
  const int sc0 = s0 + (w >> 1) * 64;

  __shared__ int len_s[16];
  if (tid < 16) {
    int L = clen[t0 + tid];
    len_s[tid] = L < 0 ? 0 : (L > T_ ? T_ : L);
  }
  __syncthreads();
  int lmax = 0;
  #pragma unroll
  for (int i = 0; i < 16; ++i) lmax = max(lmax, len_s[i]);
  if (s0 >= lmax) return;

  int lenr[4];
  #pragma unroll
  for (int r = 0; r < 4; ++r) lenr[r] = len_s[lg * 4 + r];

  bf16x8 af[8][2];
  const short* qrow = Qb + (size_t)(b * T_ + t0 + li) * E_ + hbase * DH_ + lg * 8;
  #pragma unroll
  for (int hh = 0; hh < 8; ++hh) {
    af[hh][0] = *(const bf16x8*)(qrow + hh * DH_);
    af[hh][1] = *(const bf16x8*)(qrow + hh * DH_ + 32);
  }

  float zp[8][4];
  #pragma unroll
  for (int hh = 0; hh < 8; ++hh)
    #pragma unroll
    for (int r = 0; r < 4; ++r) zp[hh][r] = 0.f;

  const short* kbase = Kb + (size_t)b * T_ * E_ + hbase * DH_ + lg * 8;
  #pragma unroll
  for (int n = 0; n < 4; ++n) {
    const int s = sc0 + n * 16 + li;
    const short* krow = kbase + (size_t)s * E_;
    #pragma unroll
    for (int hh = 0; hh < 8; ++hh) {
      const bf16x8 b0 = *(const bf16x8*)(krow + hh * DH_);
      const bf16x8 b1 = *(const bf16x8*)(krow + hh * DH_ + 32);
      f32x4 z4 = {0.f, 0.f, 0.f, 0.f};
      z4 = __builtin_amdgcn_mfma_f32_16x16x32_bf16(af[hh][0], b0, z4, 0, 0, 0);
      z4 = __builtin_amdgcn_mfma_f32_16x16x32_bf16(af[hh][1], b1, z4, 0, 0, 0);
      #pragma unroll
      for (int r = 0; r < 4; ++r)
        if (s < lenr[r]) zp[hh][r] += __expf(z4[r] * SCALE_);
    }
  }

  #pragma unroll
  for (int hh = 0; hh < 8; ++hh)
    #pragma unroll
    for (int r = 0; r < 4; ++r) {
      float v = zp[hh][r];
      #pragma unroll
      for (int off = 1; off < 16; off <<= 1) v += __shfl_xor(v, off);
      if (li == 0 && v > 0.f)
        atomicAdd(&zs[(size_t)(b * NH_ + hbase + hh) * T_ + t0 + lg * 4 + r], v);
    }
}

// --------------- K2b: attn_w -> gumbel -> EL (bf16 hi/lo), L ---------------
__global__ __launch_bounds__(256) void elgen_kernel(
    const short* __restrict__ Qb, const short* __restrict__ Kb,
    const float* __restrict__ zs, const float* __restrict__ gum,
    const int* __restrict__ clen,
    short* __restrict__ ELh, short* __restrict__ ELl, float* __restrict__ Lws)
{
  const int b = blockIdx.z;
  const int t0 = blockIdx.x * 16;
  const int s0 = blockIdx.y * 128;
  const int tid = threadIdx.x;
  const int w = tid >> 6, l = tid & 63;
  const int lg = l >> 4, li = l & 15;
  const int hbase = (w & 1) * 8;
  const int sc0 = s0 + (w >> 1) * 64;

  __shared__ float awbuf[4][16][68];
  __shared__ int len_s[16];
  if (tid < 16) {
    int L = clen[t0 + tid];
    len_s[tid] = L < 0 ? 0 : (L > T_ ? T_ : L);
  }
  __syncthreads();
  int lmax = 0;
  #pragma unroll
  for (int i = 0; i < 16; ++i) lmax = max(lmax, len_s[i]);

  const int erow = tid >> 4;              // EL-phase row
  const int ec0 = (tid & 15) * 8;         // EL-phase col base (0..120)
  const size_t myrow = (size_t)(b * T_ + t0 + erow);

  if (s0 >= lmax) {                       // fully-masked tile: zero-fill EL
    const ushort4 z4 = {0, 0, 0, 0};
    *(ushort4*)(ELh + myrow * T_ + s0 + ec0) = z4;
    *(ushort4*)(ELh + myrow * T_ + s0 + ec0 + 4) = z4;
    *(ushort4*)(ELl + myrow * T_ + s0 + ec0) = z4;
    *(ushort4*)(ELl + myrow * T_ + s0 + ec0 + 4) = z4;
    return;
  }

  bf16x8 af[8][2];
  const short* qrow = Qb + (size_t)(b * T_ + t0 + li) * E_ + hbase * DH_ + lg * 8;
  #pragma unroll
  for (int hh = 0; hh < 8; ++hh) {
    af[hh][0] = *(const bf16x8*)(qrow + hh * DH_);
    af[hh][1] = *(const bf16x8*)(qrow + hh * DH_ + 32);
  }
  float rz[8][4];
  #pragma unroll
  for (int hh = 0; hh < 8; ++hh) {
    const float* zp = zs + (size_t)(b * NH_ + hbase + hh) * T_ + t0 + lg * 4;
    #pragma unroll
    for (int r = 0; r < 4; ++r) {
      const float zv = zp[r];
      rz[hh][r] = (zv > 0.f) ? 1.f / zv : 0.f;
    }
  }

  const short* kbase = Kb + (size_t)b * T_ * E_ + hbase * DH_ + lg * 8;
  #pragma unroll
  for (int n = 0; n < 4; ++n) {
    const short* krow = kbase + (size_t)(sc0 + n * 16 + li) * E_;
    f32x4 aw = {0.f, 0.f, 0.f, 0.f};
    #pragma unroll
    for (int hh = 0; hh < 8; ++hh) {
      const bf16x8 b0 = *(const bf16x8*)(krow + hh * DH_);
      const bf16x8 b1 = *(const bf16x8*)(krow + hh * DH_ + 32);
      f32x4 z4 = {0.f, 0.f, 0.f, 0.f};
      z4 = __builtin_amdgcn_mfma_f32_16x16x32_bf16(af[hh][0], b0, z4, 0, 0, 0);
      z4 = __builtin_amdgcn_mfma_f32_16x16x32_bf16(af[hh][1], b1, z4, 0, 0, 0);
      #pragma unroll
      for (int r = 0; r < 4; ++r)
        aw[r] += __expf(z4[r] * SCALE_) * rz[hh][r];
    }
    #pragma unroll
    for (int r = 0; r < 4; ++r)
      awbuf[w][lg * 4 + r][n * 16 + li] = aw[r];
  }
  __syncthreads();

  // ---- EL phase: thread owns (erow, 8 cols) ----
  const int elen = len_s[erow];
  const int pair = ec0 >> 6;
  const int cc = ec0 & 63;
  const float4 u0 = *(const float4*)(gum + myrow * T_ + s0 + ec0);
  const float4 u1 = *(const float4*)(gum + myrow * T_ + s0 + ec0 + 4);
  float lacc = 0.f;
  ushort4 oh[2], ol[2];
  #pragma unroll
  for (int j = 0; j < 8; ++j) {
    const int s = s0 + ec0 + j;
    float e = 0.f;
    if (s < elen) {
      const float aw = awbuf[pair * 2][erow][cc + j] + awbuf[pair * 2 + 1][erow][cc + j];
      const float u = (j < 4) ? ((const float*)&u0)[j] : ((const float*)&u1)[j - 4];
      const float g = -__logf(-__logf(u));
      e = expf((aw * (1.f / NH_) + g) * 0.5f);   // /TAU, TAU=2
    }
    lacc += e;
    const short hi = f2bf(e);
    const short lo = f2bf(e - bf2f(hi));
    ((unsigned short*)&oh[j >> 2])[j & 3] = (unsigned short)hi;
    ((unsigned short*)&ol[j >> 2])[j & 3] = (unsigned short)lo;
  }
  *(ushort4*)(ELh + myrow * T_ + s0 + ec0) = oh[0];
  *(ushort4*)(ELh + myrow * T_ + s0 + ec0 + 4) = oh[1];
  *(ushort4*)(ELl + myrow * T_ + s0 + ec0) = ol[0];
  *(ushort4*)(ELl + myrow * T_ + s0 + ec0 + 4) = ol[1];

  #pragma unroll
  for (int off = 1; off < 16; off <<= 1) lacc += __shfl_xor(lacc, off);
  if (li == 0 && lacc > 0.f) atomicAdd(&Lws[myrow], lacc);
}

// ----------------------- K3: output MFMA + normalize -----------------------
__global__ __launch_bounds__(256) void out_mfma(
    const short* __restrict__ ELh, const short* __restrict__ ELl,
    const short* __restrict__ HTh, const short* __restrict__ HTl,
    const float* __restrict__ Lws, const int* __restrict__ clen,
    float* __restrict__ outp)
{
  const int e0 = blockIdx.x * 128;
  const int m0 = ((int)gridDim.y - 1 - (int)blockIdx.y) * 64;
  const int b = m0 >> 11;
  const int tl0 = m0 & (T_ - 1);
  const int tid = threadIdx.x;
  const int wid = tid >> 6, l = tid & 63;
  const int lg = l >> 4, li = l & 15;

  __shared__ __align__(16) unsigned short Ah[64][40], Al[64][40];
  __shared__ __align__(16) unsigned short Bh[128][40], Bl[128][40];
  __shared__ int smax_sh;

  if (tid == 0) smax_sh = 0;
  __syncthreads();
  if (tid < 64) {
    int L = clen[tl0 + tid];
    L = L < 0 ? 0 : (L > T_ ? T_ : L);
    atomicMax(&smax_sh, L);
  }
  __syncthreads();
  const int kend = (smax_sh + 31) & ~31;

  const int arow = tid >> 2, aq = (tid & 3) * 8;
  const int brow = tid >> 1, bq8 = (tid & 1) * 16;

  f32x4 acc[8];
  #pragma unroll
  for (int j = 0; j < 8; ++j) acc[j] = (f32x4){0.f, 0.f, 0.f, 0.f};

  for (int s0 = 0; s0 < kend; s0 += 32) {
    const bf16x8 vah = *(const bf16x8*)(ELh + (size_t)(m0 + arow) * T_ + s0 + aq);
    const bf16x8 val = *(const bf16x8*)(ELl + (size_t)(m0 + arow) * T_ + s0 + aq);
    const size_t bsrc = ((size_t)(b * E_ + e0 + brow)) * T_ + s0 + bq8;
    const bf16x8 vbh0 = *(const bf16x8*)(HTh + bsrc);
    const bf16x8 vbh1 = *(const bf16x8*)(HTh + bsrc + 8);
    const bf16x8 vbl0 = *(const bf16x8*)(HTl + bsrc);
    const bf16x8 vbl1 = *(const bf16x8*)(HTl + bsrc + 8);
    __syncthreads();
    *(bf16x8*)&Ah[arow][aq] = vah;
    *(bf16x8*)&Al[arow][aq] = val;
    *(bf16x8*)&Bh[brow][bq8] = vbh0; *(bf16x8*)&Bh[brow][bq8 + 8] = vbh1;
    *(bf16x8*)&Bl[brow][bq8] = vbl0; *(bf16x8*)&Bl[brow][bq8 + 8] = vbl1;
    __syncthreads();
    const bf16x8 ah = *(const bf16x8*)&Ah[wid * 16 + li][lg * 8];
    const bf16x8 al = *(const bf16x8*)&Al[wid * 16 + li][lg * 8];
    #pragma unroll
    for (int j = 0; j < 8; ++j) {
      const bf16x8 bh = *(const bf16x8*)&Bh[j * 16 + li][lg * 8];
      const bf16x8 bl = *(const bf16x8*)&Bl[j * 16 + li][lg * 8];
      acc[j] = __builtin_amdgcn_mfma_f32_16x16x32_bf16(ah, bh, acc[j], 0, 0, 0);
      acc[j] = __builtin_amdgcn_mfma_f32_16x16x32_bf16(ah, bl, acc[j], 0, 0, 0);
      acc[j] = __builtin_amdgcn_mfma_f32_16x16x32_bf16(al, bh, acc[j], 0, 0, 0);
    }
  }

  #pragma unroll
  for (int r = 0; r < 4; ++r) {
    const int m = m0 + wid * 16 + lg * 4 + r;
    const float Lv = Lws[m];
    const float inv = (Lv > 0.f) ? 1.f / Lv : 0.f;
    #pragma unroll
    for (int j = 0; j < 8; ++j)
      outp[(size_t)m * E_ + e0 + j * 16 + li] = acc[j][r] * inv;
  }
}

// ------------------------------- launcher ----------------------------------
extern "C" void kernel_launch(void* const* d_in, const int* in_sizes, int n_in,
                              void* d_out, int out_size, void* d_ws, size_t ws_size,
                              hipStream_t stream) {
  const float* hs  = (const float*)d_in[0];
  const float* Wq  = (const float*)d_in[1];
  const float* bq  = (const float*)d_in[2];
  const float* Wk  = (const float*)d_in[3];
  const float* bk  = (const float*)d_in[4];
  const float* gum = (const float*)d_in[5];
  const int*   cl  = (const int*)d_in[6];
  float* out = (float*)d_out;

  short* hs_hi  = (short*)d_ws;
  short* hsT_hi = hs_hi  + (size_t)M_ * E_;
  short* hsT_lo = hsT_hi + (size_t)B_ * E_ * T_;
  short* Wqb    = hsT_lo + (size_t)B_ * E_ * T_;
  short* Wkb    = Wqb + (size_t)E_ * E_;
  short* Qb     = Wkb + (size_t)E_ * E_;
  short* Kb     = Qb + (size_t)M_ * E_;
  short* ELh    = Kb + (size_t)M_ * E_;
  short* ELl    = ELh + (size_t)M_ * T_;
  float* zsws   = (float*)(ELl + (size_t)M_ * T_);
  float* Lw     = zsws + (size_t)B_ * NH_ * T_;
  (void)ws_size; (void)in_sizes; (void)n_in; (void)out_size;

  hipMemsetAsync(zsws, 0, (size_t)B_ * NH_ * T_ * sizeof(float), stream);
  hipMemsetAsync(Lw, 0, (size_t)M_ * sizeof(float), stream);
  prep_hs<<<dim3(T_ / 64, E_ / 64, B_), 256, 0, stream>>>(hs, hs_hi, hsT_hi, hsT_lo);
  cast_w<<<dim3((E_ * E_) / (256 * 4)), 256, 0, stream>>>(Wq, Wk, Wqb, Wkb);
  proj_mfma<<<dim3(16, M_ / 128), 256, 0, stream>>>(hs_hi, Wqb, Wkb, bq, bk, Qb, Kb);
  zpart_kernel<<<dim3(T_ / 16, T_ / 128, B_), 256, 0, stream>>>(Qb, Kb, cl, zsws);
  elgen_kernel<<<dim3(T_ / 16, T_ / 128, B_), 256, 0, stream>>>(
      Qb, Kb, zsws, gum, cl, ELh, ELl, Lw);
  out_mfma<<<dim3(E_ / 128, M_ / 64), 256, 0, stream>>>(
      ELh, ELl, hsT_hi, hsT_lo, Lw, cl, out);
}

// Round 5
// 285.960 us; speedup vs baseline: 1.6434x; 1.6434x over previous
//
#include <hip/hip_runtime.h>
#include <hip/hip_bf16.h>
#include <math.h>
#include <stdint.h>

// ---------------------------------------------------------------------------
// MaskedContextSelector, round 5: GEMM-structured score tiles.
//   K0a prep_hs  : hs_hi = bf16(hs); hsT_hi/lo = transposed bf16 hi/lo split
//   K0b cast_w   : Wq,Wk -> bf16
//   K1  proj_mfma: Q,K = bf16MFMA(hs_hi @ W^T) + bias -> bf16
//   K2a zpart    : z[b,h,t] via causal 128x128 LDS-staged MFMA tiles (K=64,
//                  single barrier), masked exp, shfl row-reduce, atomicAdd
//   K2b elgen    : causal 64x64 tiles, 16-head loop with LDS-staged Q/K,
//                  aw accumulated in regs; epilogue gumbel+EL(hi/lo)+L
//   K3  out_mfma : out = (ELh@Hh + ELh@Hl + ELl@Hh)/L, BK=64, padded LDS
// ---------------------------------------------------------------------------

#define B_   2
#define T_   2048
#define E_   1024
#define NH_  16
#define DH_  64
#define M_   (B_ * T_)
#define SCALE_ 0.125f

typedef __attribute__((ext_vector_type(8))) short bf16x8;
typedef __attribute__((ext_vector_type(4))) float f32x4;

__device__ __forceinline__ short f2bf(float x) {
  __hip_bfloat16 h = __float2bfloat16(x);
  return *reinterpret_cast<short*>(&h);
}
__device__ __forceinline__ float bf2f(short x) {
  __hip_bfloat16 h = *reinterpret_cast<__hip_bfloat16*>(&x);
  return __bfloat162float(h);
}
// triangular pair index -> (ti, si), si <= ti
__device__ __forceinline__ void tri_decode(int idx, int& ti, int& si) {
  int t = (int)((sqrtf(8.0f * (float)idx + 1.0f) - 1.0f) * 0.5f);
  while ((t + 1) * (t + 2) / 2 <= idx) ++t;
  while (t * (t + 1) / 2 > idx) --t;
  ti = t;
  si = idx - t * (t + 1) / 2;
}

// ------------------- K0a: cast + transpose hidden states -------------------
__global__ __launch_bounds__(256) void prep_hs(
    const float* __restrict__ hs, short* __restrict__ hs_hi,
    short* __restrict__ hsT_hi, short* __restrict__ hsT_lo)
{
  const int b = blockIdx.z;
  const int s0 = blockIdx.x * 64, e0 = blockIdx.y * 64;
  __shared__ float tile[64][65];
  const int tid = threadIdx.x;
  const int r = tid >> 4, c4 = (tid & 15) * 4;

  #pragma unroll
  for (int rr = 0; rr < 64; rr += 16) {
    const float4 v = *(const float4*)(hs + (size_t)(b * T_ + s0 + r + rr) * E_ + e0 + c4);
    ushort4 o;
    o.x = (unsigned short)f2bf(v.x); o.y = (unsigned short)f2bf(v.y);
    o.z = (unsigned short)f2bf(v.z); o.w = (unsigned short)f2bf(v.w);
    *(ushort4*)(hs_hi + (size_t)(b * T_ + s0 + r + rr) * E_ + e0 + c4) = o;
    tile[r + rr][c4 + 0] = v.x; tile[r + rr][c4 + 1] = v.y;
    tile[r + rr][c4 + 2] = v.z; tile[r + rr][c4 + 3] = v.w;
  }
  __syncthreads();
  #pragma unroll
  for (int rr = 0; rr < 64; rr += 16) {
    ushort4 oh, ol;
    #pragma unroll
    for (int j = 0; j < 4; ++j) {
      const float v = tile[c4 + j][r + rr];
      const short hi = f2bf(v);
      const short lo = f2bf(v - bf2f(hi));
      ((unsigned short*)&oh)[j] = (unsigned short)hi;
      ((unsigned short*)&ol)[j] = (unsigned short)lo;
    }
    const size_t dst = (size_t)(b * E_ + e0 + r + rr) * T_ + s0 + c4;
    *(ushort4*)(hsT_hi + dst) = oh;
    *(ushort4*)(hsT_lo + dst) = ol;
  }
}

// ------------------------------ K0b: cast W --------------------------------
__global__ __launch_bounds__(256) void cast_w(
    const float* __restrict__ Wq, const float* __restrict__ Wk,
    short* __restrict__ Wqb, short* __restrict__ Wkb)
{
  const size_t i = ((size_t)blockIdx.x * 256 + threadIdx.x) * 4;
  const float4 q = *(const float4*)(Wq + i);
  const float4 k = *(const float4*)(Wk + i);
  ushort4 oq, ok;
  oq.x = (unsigned short)f2bf(q.x); oq.y = (unsigned short)f2bf(q.y);
  oq.z = (unsigned short)f2bf(q.z); oq.w = (unsigned short)f2bf(q.w);
  ok.x = (unsigned short)f2bf(k.x); ok.y = (unsigned short)f2bf(k.y);
  ok.z = (unsigned short)f2bf(k.z); ok.w = (unsigned short)f2bf(k.w);
  *(ushort4*)(Wqb + i) = oq;
  *(ushort4*)(Wkb + i) = ok;
}

// --------------------------- K1: projection MFMA ---------------------------
__global__ __launch_bounds__(256) void proj_mfma(
    const short* __restrict__ hsb,
    const short* __restrict__ Wqb, const short* __restrict__ Wkb,
    const float* __restrict__ bq, const float* __restrict__ bk,
    short* __restrict__ Qb, short* __restrict__ Kb)
{
  const int nt = blockIdx.x;
  const int m0 = blockIdx.y * 128;
  const bool isK = nt >= 8;
  const short* __restrict__ Wsel = isK ? Wkb : Wqb;
  const float* __restrict__ bsel = isK ? bk : bq;
  short* __restrict__ Csel = isK ? Kb : Qb;
  const int nb = (nt & 7) * 128;

  __shared__ __align__(16) unsigned short Asm[128][72];
  __shared__ __align__(16) unsigned short Bsm[128][72];

  const int tid = threadIdx.x;
  const int wid = tid >> 6, l = tid & 63;
  const int lg = l >> 4, li = l & 15;
  const int wm = (wid >> 1) * 64, wn = (wid & 1) * 64;
  const int srow = tid >> 1, shalf = (tid & 1) * 32;

  f32x4 acc[4][4];
  #pragma unroll
  for (int i = 0; i < 4; ++i)
    #pragma unroll
    for (int j = 0; j < 4; ++j) acc[i][j] = (f32x4){0.f, 0.f, 0.f, 0.f};

  for (int kt = 0; kt < E_; kt += 64) {
    const short* ga = hsb + (size_t)(m0 + srow) * E_ + kt + shalf;
    const short* gb = Wsel + (size_t)(nb + srow) * E_ + kt + shalf;
    bf16x8 a0 = *(const bf16x8*)(ga);      bf16x8 a1 = *(const bf16x8*)(ga + 8);
    bf16x8 a2 = *(const bf16x8*)(ga + 16); bf16x8 a3 = *(const bf16x8*)(ga + 24);
    bf16x8 b0 = *(const bf16x8*)(gb);      bf16x8 b1 = *(const bf16x8*)(gb + 8);
    bf16x8 b2 = *(const bf16x8*)(gb + 16); bf16x8 b3 = *(const bf16x8*)(gb + 24);
    __syncthreads();
    *(bf16x8*)&Asm[srow][shalf + 0]  = a0; *(bf16x8*)&Asm[srow][shalf + 8]  = a1;
    *(bf16x8*)&Asm[srow][shalf + 16] = a2; *(bf16x8*)&Asm[srow][shalf + 24] = a3;
    *(bf16x8*)&Bsm[srow][shalf + 0]  = b0; *(bf16x8*)&Bsm[srow][shalf + 8]  = b1;
    *(bf16x8*)&Bsm[srow][shalf + 16] = b2; *(bf16x8*)&Bsm[srow][shalf + 24] = b3;
    __syncthreads();
    #pragma unroll
    for (int kb = 0; kb < 2; ++kb) {
      bf16x8 af[4], bfv[4];
      #pragma unroll
      for (int i = 0; i < 4; ++i)
        af[i] = *(const bf16x8*)&Asm[wm + i * 16 + li][kb * 32 + lg * 8];
      #pragma unroll
      for (int j = 0; j < 4; ++j)
        bfv[j] = *(const bf16x8*)&Bsm[wn + j * 16 + li][kb * 32 + lg * 8];
      #pragma unroll
      for (int i = 0; i < 4; ++i)
        #pragma unroll
        for (int j = 0; j < 4; ++j)
          acc[i][j] = __builtin_amdgcn_mfma_f32_16x16x32_bf16(af[i], bfv[j], acc[i][j], 0, 0, 0);
    }
  }

  #pragma unroll
  for (int j = 0; j < 4; ++j) {
    const int n = nb + wn + j * 16 + li;
    const float bv = bsel[n];
    #pragma unroll
    for (int i = 0; i < 4; ++i) {
      #pragma unroll
      for (int r = 0; r < 4; ++r) {
        const int m = m0 + wm + i * 16 + lg * 4 + r;
        Csel[(size_t)m * E_ + n] = f2bf(acc[i][j][r] + bv);
      }
    }
  }
}

// ----------------- K2a: z sums via causal 128x128 GEMM tiles ---------------
__global__ __launch_bounds__(256) void zpart_kernel(
    const short* __restrict__ Qb, const short* __restrict__ Kb,
    const int* __restrict__ clen, float* __restrict__ zs)
{
  const int bh = blockIdx.y;
  const int b = bh >> 4, h = bh & 15;
  int ti, si;
  tri_decode(blockIdx.x, ti, si);
  const int t0 = ti * 128, s0 = si * 128;
  const int tid = threadIdx.x;
  const int w = tid >> 6, l = tid & 63, lg = l >> 4, li = l & 15;
  const int wm = (w >> 1) * 64, wn = (w & 1) * 64;

  __shared__ __align__(16) unsigned short Qs[128][72];
  __shared__ __align__(16) unsigned short Ks[128][72];
  __shared__ int len_s[128];

  {
    const int row = tid >> 1, half = (tid & 1) * 32;
    const short* gq = Qb + (size_t)(b * T_ + t0 + row) * E_ + h * DH_ + half;
    const short* gk = Kb + (size_t)(b * T_ + s0 + row) * E_ + h * DH_ + half;
    *(bf16x8*)&Qs[row][half + 0]  = *(const bf16x8*)(gq + 0);
    *(bf16x8*)&Qs[row][half + 8]  = *(const bf16x8*)(gq + 8);
    *(bf16x8*)&Qs[row][half + 16] = *(const bf16x8*)(gq + 16);
    *(bf16x8*)&Qs[row][half + 24] = *(const bf16x8*)(gq + 24);
    *(bf16x8*)&Ks[row][half + 0]  = *(const bf16x8*)(gk + 0);
    *(bf16x8*)&Ks[row][half + 8]  = *(const bf16x8*)(gk + 8);
    *(bf16x8*)&Ks[row][half + 16] = *(const bf16x8*)(gk + 16);
    *(bf16x8*)&Ks[row][half + 24] = *(const bf16x8*)(gk + 24);
  }
  if (tid < 128) {
    int L = clen[t0 + tid];
    len_s[tid] = L < 0 ? 0 : (L > T_ ? T_ : L);
  }
  __syncthreads();

  f32x4 acc[4][4];
  #pragma unroll
  for (int i = 0; i < 4; ++i)
    #pragma unroll
    for (int j = 0; j < 4; ++j) acc[i][j] = (f32x4){0.f, 0.f, 0.f, 0.f};

  #pragma unroll
  for (int kb = 0; kb < 2; ++kb) {
    bf16x8 af[4], bfv[4];
    #pragma unroll
    for (int i = 0; i < 4; ++i)
      af[i] = *(const bf16x8*)&Qs[wm + i * 16 + li][kb * 32 + lg * 8];
    #pragma unroll
    for (int j = 0; j < 4; ++j)
      bfv[j] = *(const bf16x8*)&Ks[wn + j * 16 + li][kb * 32 + lg * 8];
    #pragma unroll
    for (int i = 0; i < 4; ++i)
      #pragma unroll
      for (int j = 0; j < 4; ++j)
        acc[i][j] = __builtin_amdgcn_mfma_f32_16x16x32_bf16(af[i], bfv[j], acc[i][j], 0, 0, 0);
  }

  float zp[4][4];
  #pragma unroll
  for (int i = 0; i < 4; ++i)
    #pragma unroll
    for (int r = 0; r < 4; ++r) zp[i][r] = 0.f;

  #pragma unroll
  for (int i = 0; i < 4; ++i) {
    int lenr[4];
    #pragma unroll
    for (int r = 0; r < 4; ++r) lenr[r] = len_s[wm + i * 16 + lg * 4 + r];
    #pragma unroll
    for (int j = 0; j < 4; ++j) {
      const int scol = s0 + wn + j * 16 + li;
      #pragma unroll
      for (int r = 0; r < 4; ++r)
        if (scol < lenr[r]) zp[i][r] += __expf(acc[i][j][r] * SCALE_);
    }
  }

  #pragma unroll
  for (int i = 0; i < 4; ++i)
    #pragma unroll
    for (int r = 0; r < 4; ++r) {
      float v = zp[i][r];
      v += __shfl_xor(v, 1); v += __shfl_xor(v, 2);
      v += __shfl_xor(v, 4); v += __shfl_xor(v, 8);
      if (li == 0 && v > 0.f)
        atomicAdd(&zs[(size_t)bh * T_ + t0 + wm + i * 16 + lg * 4 + r], v);
    }
}

// ------------- K2b: causal 64x64 tiles, 16-head loop, EL + L ---------------
__global__ __launch_bounds__(256) void elgen_kernel(
    const short* __restrict__ Qb, const short* __restrict__ Kb,
    const float* __restrict__ zs, const float* __restrict__ gum,
    const int* __restrict__ clen,
    short* __restrict__ ELh, short* __restrict__ ELl, float* __restrict__ Lws)
{
  const int b = blockIdx.y;
  int ti, si;
  tri_decode(blockIdx.x, ti, si);
  const int t0 = ti * 64, s0 = si * 64;
  const int tid = threadIdx.x;
  const int w = tid >> 6, l = tid & 63, lg = l >> 4, li = l & 15;
  const int wr = (w >> 1) * 32, wc = (w & 1) * 32;

  __shared__ __align__(16) unsigned short Qs[64][72];
  __shared__ __align__(16) unsigned short Ks[64][72];
  __shared__ float rz_s[16][64];
  __shared__ int len_s[64];

  if (tid < 64) {
    int L = clen[t0 + tid];
    len_s[tid] = L < 0 ? 0 : (L > T_ ? T_ : L);
  }
  #pragma unroll
  for (int q = 0; q < 4; ++q) {
    const int e = tid * 4 + q;                    // 0..1023 = h*64 + tl
    const float zv = zs[(size_t)(b * NH_ + (e >> 6)) * T_ + t0 + (e & 63)];
    rz_s[e >> 6][e & 63] = (zv > 0.f) ? 1.f / zv : 0.f;
  }

  f32x4 aw[2][2];
  #pragma unroll
  for (int i = 0; i < 2; ++i)
    #pragma unroll
    for (int j = 0; j < 2; ++j) aw[i][j] = (f32x4){0.f, 0.f, 0.f, 0.f};

  const int srow = tid >> 2, sch = (tid & 3) * 16;

  for (int h = 0; h < NH_; ++h) {
    __syncthreads();   // h=0: covers len_s/rz_s writes; h>0: protect LDS reuse
    const short* gq = Qb + (size_t)(b * T_ + t0 + srow) * E_ + h * DH_ + sch;
    const short* gk = Kb + (size_t)(b * T_ + s0 + srow) * E_ + h * DH_ + sch;
    *(bf16x8*)&Qs[srow][sch + 0] = *(const bf16x8*)(gq);
    *(bf16x8*)&Qs[srow][sch + 8] = *(const bf16x8*)(gq + 8);
    *(bf16x8*)&Ks[srow][sch + 0] = *(const bf16x8*)(gk);
    *(bf16x8*)&Ks[srow][sch + 8] = *(const bf16x8*)(gk + 8);
    __syncthreads();

    f32x4 sc[2][2];
    #pragma unroll
    for (int i = 0; i < 2; ++i)
      #pragma unroll
      for (int j = 0; j < 2; ++j) sc[i][j] = (f32x4){0.f, 0.f, 0.f, 0.f};
    #pragma unroll
    for (int kb = 0; kb < 2; ++kb) {
      bf16x8 af[2], bfv[2];
      af[0] = *(const bf16x8*)&Qs[wr + li][kb * 32 + lg * 8];
      af[1] = *(const bf16x8*)&Qs[wr + 16 + li][kb * 32 + lg * 8];
      bfv[0] = *(const bf16x8*)&Ks[wc + li][kb * 32 + lg * 8];
      bfv[1] = *(const bf16x8*)&Ks[wc + 16 + li][kb * 32 + lg * 8];
      #pragma unroll
      for (int i = 0; i < 2; ++i)
        #pragma unroll
        for (int j = 0; j < 2; ++j)
          sc[i][j] = __builtin_amdgcn_mfma_f32_16x16x32_bf16(af[i], bfv[j], sc[i][j], 0, 0, 0);
    }
    #pragma unroll
    for (int i = 0; i < 2; ++i) {
      float rzv[4];
      #pragma unroll
      for (int r = 0; r < 4; ++r) rzv[r] = rz_s[h][wr + i * 16 + lg * 4 + r];
      #pragma unroll
      for (int j = 0; j < 2; ++j)
        #pragma unroll
        for (int r = 0; r < 4; ++r)
          aw[i][j][r] += __expf(sc[i][j][r] * SCALE_) * rzv[r];
    }
  }

  // epilogue: gumbel -> EL hi/lo stores + L row partials
  float lrow[2][4];
  #pragma unroll
  for (int i = 0; i < 2; ++i)
    #pragma unroll
    for (int r = 0; r < 4; ++r) lrow[i][r] = 0.f;

  #pragma unroll
  for (int i = 0; i < 2; ++i) {
    #pragma unroll
    for (int r = 0; r < 4; ++r) {
      const int tl = wr + i * 16 + lg * 4 + r;
      const int lenr = len_s[tl];
      const size_t grow = (size_t)(b * T_ + t0 + tl) * T_;
      #pragma unroll
      for (int j = 0; j < 2; ++j) {
        const int scol = s0 + wc + j * 16 + li;
        float e = 0.f;
        if (scol < lenr) {
          const float u = gum[grow + scol];
          const float g = -__logf(-__logf(u));
          e = expf((aw[i][j][r] * (1.f / NH_) + g) * 0.5f);   // /TAU, TAU=2
        }
        const short hi = f2bf(e);
        const short lo = f2bf(e - bf2f(hi));
        ELh[grow + scol] = hi;
        ELl[grow + scol] = lo;
        lrow[i][r] += e;
      }
    }
  }

  #pragma unroll
  for (int i = 0; i < 2; ++i)
    #pragma unroll
    for (int r = 0; r < 4; ++r) {
      float v = lrow[i][r];
      v += __shfl_xor(v, 1); v += __shfl_xor(v, 2);
      v += __shfl_xor(v, 4); v += __shfl_xor(v, 8);
      if (li == 0 && v > 0.f)
        atomicAdd(&Lws[(size_t)(b * T_) + t0 + wr + i * 16 + lg * 4 + r], v);
    }
}

// ----------------------- K3: output MFMA + normalize -----------------------
__global__ __launch_bounds__(256) void out_mfma(
    const short* __restrict__ ELh, const short* __restrict__ ELl,
    const short* __restrict__ HTh, const short* __restrict__ HTl,
    const float* __restrict__ Lws, const int* __restrict__ clen,
    float* __restrict__ outp)
{
  const int e0 = blockIdx.x * 128;
  const int m0 = ((int)gridDim.y - 1 - (int)blockIdx.y) * 64;   // long tiles first
  const int b = m0 >> 11;
  const int tl0 = m0 & (T_ - 1);
  const int tid = threadIdx.x;
  const int w = tid >> 6, l = tid & 63, lg = l >> 4, li = l & 15;
  const int wr = (w >> 1) * 32, wc = (w & 1) * 64;

  __shared__ __align__(16) unsigned short Ah[64][72], Al[64][72];
  __shared__ __align__(16) unsigned short Bh[128][72], Bl[128][72];
  __shared__ int smax_sh;

  if (tid == 0) smax_sh = 0;
  __syncthreads();
  if (tid < 64) {
    int L = clen[tl0 + tid];
    L = L < 0 ? 0 : (L > T_ ? T_ : L);
    atomicMax(&smax_sh, L);
  }
  __syncthreads();
  const int kend = (smax_sh + 63) & ~63;

  const int ar = tid >> 2, ac = (tid & 3) * 16;
  const int br = tid >> 1, bc = (tid & 1) * 32;

  f32x4 acc[2][4];
  #pragma unroll
  for (int i = 0; i < 2; ++i)
    #pragma unroll
    for (int j = 0; j < 4; ++j) acc[i][j] = (f32x4){0.f, 0.f, 0.f, 0.f};

  for (int s0 = 0; s0 < kend; s0 += 64) {
    const size_t asrc = (size_t)(m0 + ar) * T_ + s0 + ac;
    const size_t bsrc = (size_t)(b * E_ + e0 + br) * T_ + s0 + bc;
    const bf16x8 vah0 = *(const bf16x8*)(ELh + asrc);
    const bf16x8 vah1 = *(const bf16x8*)(ELh + asrc + 8);
    const bf16x8 val0 = *(const bf16x8*)(ELl + asrc);
    const bf16x8 val1 = *(const bf16x8*)(ELl + asrc + 8);
    const bf16x8 vbh0 = *(const bf16x8*)(HTh + bsrc);
    const bf16x8 vbh1 = *(const bf16x8*)(HTh + bsrc + 8);
    const bf16x8 vbh2 = *(const bf16x8*)(HTh + bsrc + 16);
    const bf16x8 vbh3 = *(const bf16x8*)(HTh + bsrc + 24);
    const bf16x8 vbl0 = *(const bf16x8*)(HTl + bsrc);
    const bf16x8 vbl1 = *(const bf16x8*)(HTl + bsrc + 8);
    const bf16x8 vbl2 = *(const bf16x8*)(HTl + bsrc + 16);
    const bf16x8 vbl3 = *(const bf16x8*)(HTl + bsrc + 24);
    __syncthreads();
    *(bf16x8*)&Ah[ar][ac + 0] = vah0; *(bf16x8*)&Ah[ar][ac + 8] = vah1;
    *(bf16x8*)&Al[ar][ac + 0] = val0; *(bf16x8*)&Al[ar][ac + 8] = val1;
    *(bf16x8*)&Bh[br][bc + 0]  = vbh0; *(bf16x8*)&Bh[br][bc + 8]  = vbh1;
    *(bf16x8*)&Bh[br][bc + 16] = vbh2; *(bf16x8*)&Bh[br][bc + 24] = vbh3;
    *(bf16x8*)&Bl[br][bc + 0]  = vbl0; *(bf16x8*)&Bl[br][bc + 8]  = vbl1;
    *(bf16x8*)&Bl[br][bc + 16] = vbl2; *(bf16x8*)&Bl[br][bc + 24] = vbl3;
    __syncthreads();
    #pragma unroll
    for (int kb = 0; kb < 2; ++kb) {
      bf16x8 ah[2], al[2], bh[4], bl[4];
      #pragma unroll
      for (int i = 0; i < 2; ++i) {
        ah[i] = *(const bf16x8*)&Ah[wr + i * 16 + li][kb * 32 + lg * 8];
        al[i] = *(const bf16x8*)&Al[wr + i * 16 + li][kb * 32 + lg * 8];
      }
      #pragma unroll
      for (int j = 0; j < 4; ++j) {
        bh[j] = *(const bf16x8*)&Bh[wc + j * 16 + li][kb * 32 + lg * 8];
        bl[j] = *(const bf16x8*)&Bl[wc + j * 16 + li][kb * 32 + lg * 8];
      }
      #pragma unroll
      for (int i = 0; i < 2; ++i)
        #pragma unroll
        for (int j = 0; j < 4; ++j) {
          acc[i][j] = __builtin_amdgcn_mfma_f32_16x16x32_bf16(ah[i], bh[j], acc[i][j], 0, 0, 0);
          acc[i][j] = __builtin_amdgcn_mfma_f32_16x16x32_bf16(ah[i], bl[j], acc[i][j], 0, 0, 0);
          acc[i][j] = __builtin_amdgcn_mfma_f32_16x16x32_bf16(al[i], bh[j], acc[i][j], 0, 0, 0);
        }
    }
  }

  #pragma unroll
  for (int i = 0; i < 2; ++i)
    #pragma unroll
    for (int r = 0; r < 4; ++r) {
      const int m = m0 + wr + i * 16 + lg * 4 + r;
      const float Lv = Lws[m];
      const float inv = (Lv > 0.f) ? 1.f / Lv : 0.f;
      #pragma unroll
      for (int j = 0; j < 4; ++j)
        outp[(size_t)m * E_ + e0 + wc + j * 16 + li] = acc[i][j][r] * inv;
    }
}

// ------------------------------- launcher ----------------------------------
extern "C" void kernel_launch(void* const* d_in, const int* in_sizes, int n_in,
                              void* d_out, int out_size, void* d_ws, size_t ws_size,
                              hipStream_t stream) {
  const float* hs  = (const float*)d_in[0];
  const float* Wq  = (const float*)d_in[1];
  const float* bq  = (const float*)d_in[2];
  const float* Wk  = (const float*)d_in[3];
  const float* bk  = (const float*)d_in[4];
  const float* gum = (const float*)d_in[5];
  const int*   cl  = (const int*)d_in[6];
  float* out = (float*)d_out;

  short* hs_hi  = (short*)d_ws;
  short* hsT_hi = hs_hi  + (size_t)M_ * E_;
  short* hsT_lo = hsT_hi + (size_t)B_ * E_ * T_;
  short* Wqb    = hsT_lo + (size_t)B_ * E_ * T_;
  short* Wkb    = Wqb + (size_t)E_ * E_;
  short* Qb     = Wkb + (size_t)E_ * E_;
  short* Kb     = Qb + (size_t)M_ * E_;
  short* ELh    = Kb + (size_t)M_ * E_;
  short* ELl    = ELh + (size_t)M_ * T_;
  float* zsws   = (float*)(ELl + (size_t)M_ * T_);
  float* Lw     = zsws + (size_t)B_ * NH_ * T_;
  (void)ws_size; (void)in_sizes; (void)n_in; (void)out_size;

  hipMemsetAsync(zsws, 0, (size_t)B_ * NH_ * T_ * sizeof(float), stream);
  hipMemsetAsync(Lw, 0, (size_t)M_ * sizeof(float), stream);
  prep_hs<<<dim3(T_ / 64, E_ / 64, B_), 256, 0, stream>>>(hs, hs_hi, hsT_hi, hsT_lo);
  cast_w<<<dim3((E_ * E_) / (256 * 4)), 256, 0, stream>>>(Wq, Wk, Wqb, Wkb);
  proj_mfma<<<dim3(16, M_ / 128), 256, 0, stream>>>(hs_hi, Wqb, Wkb, bq, bk, Qb, Kb);
  zpart_kernel<<<dim3(136, B_ * NH_), 256, 0, stream>>>(Qb, Kb, cl, zsws);
  elgen_kernel<<<dim3(528, B_), 256, 0, stream>>>(Qb, Kb, zsws, gum, cl, ELh, ELl, Lw);
  out_mfma<<<dim3(E_ / 128, M_ / 64), 256, 0, stream>>>(
      ELh, ELl, hsT_hi, hsT_lo, Lw, cl, out);
}